// Round 7
// baseline (693.123 us; speedup 1.0000x reference)
//
#include <hip/hip_runtime.h>
#include <hip/hip_bf16.h>

#define TXT   512
#define REDUX 64
#define IMG   2048
#define REFN  512
#define NC    2
#define SEQ   3168
#define DH    128
#define NH    24
#define TRE   576
#define TRI   2624
#define TRIR  3136
#define SCALE 0.08838834764831845f
#define L2E   1.4426950408889634f
#define QSC   (SCALE * L2E)          // scale folded with log2(e)
#define C100  (100.0f * L2E)         // 144.2695
#define CREF  (98.5f * L2E)          // 142.1055
#define THR2  (4.0f * L2E)           // defer-max threshold in log2 units

using f32x4  = __attribute__((ext_vector_type(4))) float;
using short8 = __attribute__((ext_vector_type(8))) short;

__device__ inline short f2bf(float x) {
    union { __hip_bfloat16 b; short s; } u;
    u.b = __float2bfloat16(x);
    return u.s;
}

__device__ inline void gload16(const short* g, short* l) {
    __builtin_amdgcn_global_load_lds(
        (const __attribute__((address_space(1))) unsigned int*)g,
        (__attribute__((address_space(3))) unsigned int*)l, 16, 0, 0);
}

// ---------------- fused pre-pass: K f32->bf16 linear, V f32->bf16 transposed ----------------
__global__ void cvt_kv_kernel(const float* __restrict__ K, const float* __restrict__ V,
                              short* __restrict__ Kb, short* __restrict__ Vt) {
    const int h   = blockIdx.y;
    const int tid = threadIdx.x;
    {
        const int base = ((h * SEQ + blockIdx.x * 16) * DH) >> 2;   // float4 idx
        #pragma unroll
        for (int j = 0; j < 2; ++j) {
            const int i = base + tid + j * 256;
            const float4 v = ((const float4*)K)[i];
            short4 o;
            o.x = f2bf(v.x); o.y = f2bf(v.y); o.z = f2bf(v.z); o.w = f2bf(v.w);
            ((short4*)Kb)[i] = o;
        }
    }
    {
        const int s8 = blockIdx.x * 2 + (tid >> 7);
        const int d  = tid & 127;
        const int s0 = s8 * 8;
        const float* src = V + ((size_t)h * SEQ + s0) * DH + d;
        short8 w;
        #pragma unroll
        for (int j = 0; j < 8; ++j) w[j] = f2bf(src[j * DH]);
        short* dst = Vt + ((size_t)h * DH + d) * SEQ + s0;
        *(short8*)dst = w;
    }
}

// ---------------- MFMA flash attention: all regions, counted-vmcnt pipeline ----------------
__global__ __launch_bounds__(512, 4)
void attn_mfma(const float* __restrict__ Q, const short* __restrict__ Kb,
               const short* __restrict__ Vtg, const float* __restrict__ ref_mask,
               const float* __restrict__ routing, float* __restrict__ out)
{
    __shared__ short Ks[2][64 * 128];   // [buf][key][chunk^(key&7)] bf16
    __shared__ short Vs[2][128 * 64];   // [buf][d][kc^(d&7)] bf16
    __shared__ short Pl[8][16 * 64];    // per-wave P, swizzled

    const int bid  = blockIdx.x;
    const int h    = bid % NH;          // same head -> same (bid%8) -> same XCD
    const int bx   = bid / NH;          // 0..25, heavy blocks dispatch first
    const int tid  = threadIdx.x;
    const int wave = tid >> 6, lane = tid & 63;
    const int g    = lane >> 4, l4 = lane & 15;

    int qbase, ks0 = 0, ntiles;
    bool masked = false, router = false;
    if (bx < 21)       { qbase = bx * 128; ntiles = 49; masked = true; }
    else if (bx == 21) { qbase = TRIR; ntiles = 33; router = true; }
    else {
        const int b2 = bx - 22;
        qbase = TRI + b2 * 128;
        ks0 = TRI + (b2 >> 1) * 256; ntiles = 4;
    }

    const int rbase = qbase + wave * 16;             // this wave's 16 q rows
    const bool valid = !(masked && rbase >= TRI) && !(router && wave >= 2);

    // ---- staging address precompute (pre-swizzled global source, linear LDS dest) ----
    const short* KbH = Kb  + (size_t)h * SEQ * DH;
    const short* VtH = Vtg + (size_t)h * DH * SEQ;
    int koff[2], vD[2], vKC[2], voff[2];
    #pragma unroll
    for (int j = 0; j < 2; ++j) {
        const int ci = tid + j * 512;
        const int kk = ci >> 4, kc = ci & 15;
        koff[j] = kk * 128 + ((kc ^ (kk & 7)) << 3);
        const int vd = ci >> 3, vk = ci & 7;
        vD[j] = vd; vKC[j] = vk;
        voff[j] = vd * SEQ + ((vk ^ (vd & 7)) << 3);
    }

    // tile index -> key offset
    auto tile_kt = [&](int tt) -> int {
        return masked ? tt * 64 : (router ? (tt < 32 ? TRE + tt * 64 : TRIR) : ks0 + tt * 64);
    };
    // issue async stage of tile tt into buffer b (4 global_load_lds per wave)
    auto stage = [&](int tt, int b) {
        const int kt  = tile_kt(tt);
        const bool tl = router && (tt == 32);
        const short* kb = KbH + (size_t)kt * DH;
        const short* vb = VtH + kt;
        short* ksb = &Ks[b][wave * 512];
        short* vsb = &Vs[b][wave * 512];
        const int ko0 = tl ? (koff[0] & 4095) : koff[0];
        const int ko1 = tl ? (koff[1] & 4095) : koff[1];
        gload16(kb + ko0, ksb);
        gload16(kb + ko1, ksb + 4096);
        const int vo0 = tl ? (vD[0] * SEQ + (((vKC[0] ^ (vD[0] & 7)) & 3) << 3)) : voff[0];
        const int vo1 = tl ? (vD[1] * SEQ + (((vKC[1] ^ (vD[1] & 7)) & 3) << 3)) : voff[1];
        gload16(vb + vo0, vsb);
        gload16(vb + vo1, vsb + 4096);
    };

    // ---- Q fragments (pre-scaled to log2 domain, bf16): row = l4, k-chunk = ks*4+g ----
    short8 qA[4];
    if (valid) {
        const int q = rbase + l4;
        const float* qp = Q + ((size_t)h * SEQ + q) * DH;
        #pragma unroll
        for (int ks = 0; ks < 4; ++ks) {
            const float4 a = *(const float4*)(qp + ks * 32 + g * 8);
            const float4 b = *(const float4*)(qp + ks * 32 + g * 8 + 4);
            short8 f;
            f[0] = f2bf(a.x * QSC); f[1] = f2bf(a.y * QSC);
            f[2] = f2bf(a.z * QSC); f[3] = f2bf(a.w * QSC);
            f[4] = f2bf(b.x * QSC); f[5] = f2bf(b.y * QSC);
            f[6] = f2bf(b.z * QSC); f[7] = f2bf(b.w * QSC);
            qA[ks] = f;
        }
    }

    f32x4 acc[8] = {};
    f32x4 m_run, l_run;
    #pragma unroll
    for (int r = 0; r < 4; ++r) { m_run[r] = -3.0e38f; l_run[r] = 0.f; }

    const int swl = (l4 & 7) ^ ((l4 >> 3) << 1);     // P read-side swizzle for row=l4

    // ---- pipeline prologue: tiles 0 and 1 in flight (8 loads/wave) ----
    stage(0, 0);
    stage(1, 1);
    int cur = 0;

    for (int t = 0; t < ntiles; ++t) {
        // counted wait: leave next tile's 4 loads in flight (never drain mid-loop)
        if (t + 1 < ntiles) asm volatile("s_waitcnt vmcnt(4)" ::: "memory");
        else                asm volatile("s_waitcnt vmcnt(0)" ::: "memory");
        __builtin_amdgcn_sched_barrier(0);
        __builtin_amdgcn_s_barrier();                // all waves' tile-t loads landed

        if (valid) {
            const int kt   = tile_kt(t);
            const bool tail = router && (t == 32);
            const short* KsC = Ks[cur];
            const short* VsC = Vs[cur];

            // ---- hoisted mask loads (latency hides under QK^T MFMAs) ----
            f32x4 rm[4]; f32x4 rt = {}; f32x4 rt0, rt1;
            bool hr = false;
            const bool refTile = masked && (kt >= TRI);
            const bool rdxTile = masked && (kt == TXT) && (rbase >= TRE);
            if (refTile) {
                const int cr = (kt - TRI) >> 8;
                const int q0 = rbase + g * 4;
                hr = rbase >= TRE;
                if (hr) rt = *(const f32x4*)(routing + cr * IMG + (q0 - TRE));
                #pragma unroll
                for (int nt = 0; nt < 4; ++nt) {
                    const int j = kt - TRI + nt * 16 + l4;
                    rm[nt] = *(const f32x4*)(ref_mask + (size_t)j * TRI + q0);
                }
            } else if (rdxTile) {
                const int q0 = rbase + g * 4;
                rt0 = *(const f32x4*)(routing + (q0 - TRE));
                rt1 = *(const f32x4*)(routing + IMG + (q0 - TRE));
            }

            // ---- QK^T ----
            f32x4 s[4] = {};
            __builtin_amdgcn_s_setprio(1);
            #pragma unroll
            for (int nt = 0; nt < 4; ++nt) {
                const int key = nt * 16 + l4;
                #pragma unroll
                for (int ks = 0; ks < 4; ++ks) {
                    const short8 kB = *(const short8*)(KsC + key * 128 + (((ks * 4 + g) ^ (key & 7)) << 3));
                    s[nt] = __builtin_amdgcn_mfma_f32_16x16x32_bf16(qA[ks], kB, s[nt], 0, 0, 0);
                }
            }
            __builtin_amdgcn_s_setprio(0);

            // ---- apply masks (f32 exact, log2 domain) ----
            if (refTile) {
                #pragma unroll
                for (int nt = 0; nt < 4; ++nt)
                    #pragma unroll
                    for (int r = 0; r < 4; ++r) {
                        float add = rm[nt][r] * C100 - CREF;
                        if (hr) add += rt[r] * C100 - C100;
                        s[nt][r] += add;
                    }
            } else if (rdxTile) {
                #pragma unroll
                for (int nt = 0; nt < 4; ++nt)
                    #pragma unroll
                    for (int r = 0; r < 4; ++r)
                        s[nt][r] += (((nt >> 1) ? rt1[r] : rt0[r])) * C100 - C100;
            }
            if (tail) {                              // router tail: keys >= SEQ invalid
                #pragma unroll
                for (int r = 0; r < 4; ++r) { s[2][r] = -3.0e38f; s[3][r] = -3.0e38f; }
            }

            // ---- online softmax (log2 domain) with defer-max ----
            f32x4 mx = s[0];
            #pragma unroll
            for (int nt = 1; nt < 4; ++nt)
                #pragma unroll
                for (int r = 0; r < 4; ++r) mx[r] = fmaxf(mx[r], s[nt][r]);
            #pragma unroll
            for (int dd = 1; dd < 16; dd <<= 1)
                #pragma unroll
                for (int r = 0; r < 4; ++r) mx[r] = fmaxf(mx[r], __shfl_xor(mx[r], dd));

            float gmax = fmaxf(fmaxf(mx[0] - m_run[0], mx[1] - m_run[1]),
                               fmaxf(mx[2] - m_run[2], mx[3] - m_run[3]));
            if (__any(gmax > THR2)) {
                f32x4 corr;
                #pragma unroll
                for (int r = 0; r < 4; ++r) {
                    const float mn = fmaxf(m_run[r], mx[r]);
                    corr[r] = exp2f(m_run[r] - mn);
                    m_run[r] = mn;
                    l_run[r] *= corr[r];
                }
                #pragma unroll
                for (int nt = 0; nt < 8; ++nt)
                    #pragma unroll
                    for (int r = 0; r < 4; ++r) acc[nt][r] *= corr[r];
            }

            f32x4 rs = {};
            #pragma unroll
            for (int nt = 0; nt < 4; ++nt)
                #pragma unroll
                for (int r = 0; r < 4; ++r) {
                    s[nt][r] = exp2f(s[nt][r] - m_run[r]);
                    rs[r] += s[nt][r];
                }
            #pragma unroll
            for (int dd = 1; dd < 16; dd <<= 1)
                #pragma unroll
                for (int r = 0; r < 4; ++r) rs[r] += __shfl_xor(rs[r], dd);
            #pragma unroll
            for (int r = 0; r < 4; ++r) l_run[r] += rs[r];

            // ---- P (C/D layout) -> per-wave LDS ----
            #pragma unroll
            for (int nt = 0; nt < 4; ++nt)
                #pragma unroll
                for (int r = 0; r < 4; ++r) {
                    const int row = g * 4 + r;
                    const int sw  = (row & 7) ^ ((row >> 3) << 1);
                    const int col = nt * 16 + l4;
                    Pl[wave][row * 64 + (col ^ (sw << 3))] = f2bf(s[nt][r]);
                }

            // ---- PV ----
            __builtin_amdgcn_s_setprio(1);
            #pragma unroll
            for (int ks2 = 0; ks2 < 2; ++ks2) {
                const short8 pA = *(const short8*)(&Pl[wave][l4 * 64 + (((ks2 * 4 + g) ^ swl) << 3)]);
                #pragma unroll
                for (int nt = 0; nt < 8; ++nt) {
                    const int d = nt * 16 + l4;
                    const short8 vB = *(const short8*)(VsC + d * 64 + (((ks2 * 4 + g) ^ (d & 7)) << 3));
                    acc[nt] = __builtin_amdgcn_mfma_f32_16x16x32_bf16(pA, vB, acc[nt], 0, 0, 0);
                }
            }
            __builtin_amdgcn_s_setprio(0);
        }

        __builtin_amdgcn_s_barrier();                // all waves done reading buf[cur]
        if (t + 2 < ntiles) stage(t + 2, cur);       // refill freed buffer
        cur ^= 1;
    }

    if (valid) {
        #pragma unroll
        for (int nt = 0; nt < 8; ++nt)
            #pragma unroll
            for (int r = 0; r < 4; ++r) {
                const int q = rbase + g * 4 + r;
                out[((size_t)h * SEQ + q) * DH + nt * 16 + l4] = acc[nt][r] / l_run[r];
            }
    }
}

// ---------------- scalar kernel (full fallback only) ----------------
#define KT  32
#define LDK (DH + 4)
__global__ __launch_bounds__(256, 2)
void anystory_attn_scalar(const float* __restrict__ Q, const float* __restrict__ K,
                          const float* __restrict__ V, const float* __restrict__ ref_mask,
                          const float* __restrict__ routing, float* __restrict__ out, int row0)
{
    __shared__ float KsS[KT][LDK];
    __shared__ float VsS[KT][LDK];

    const int h    = blockIdx.y;
    const int r0   = row0 + blockIdx.x * 4;
    const int tid  = threadIdx.x;
    const int wave = tid >> 6;
    const int lane = tid & 63;
    const int key_l = lane & 31;
    const int half  = lane >> 5;
    const int row  = r0 + wave;

    int rs0, re0, rs1 = 0, re1 = 0;
    bool masked = false;
    if (r0 < TRI) { rs0 = 0; re0 = TRIR; masked = true; }
    else if (r0 < TRIR) {
        int c = (r0 - TRI) / (REFN / NC);
        rs0 = TRI + c * (REFN / NC); re0 = rs0 + (REFN / NC);
    } else { rs0 = TRE; re0 = TRI; rs1 = TRIR; re1 = SEQ; }

    float4 qreg[16];
    const float4* qptr = (const float4*)(Q + ((size_t)h * SEQ + row) * DH + half * 64);
    #pragma unroll
    for (int i = 0; i < 16; ++i) qreg[i] = qptr[i];

    float m = -1e30f, l = 0.f, acc0 = 0.f, acc1 = 0.f;

    for (int range = 0; range < 2; ++range) {
        const int ks = (range == 0) ? rs0 : rs1;
        const int ke = (range == 0) ? re0 : re1;
        for (int kt = ks; kt < ke; kt += KT) {
            __syncthreads();
            #pragma unroll
            for (int i = 0; i < 4; ++i) {
                int idx = tid + i * 256;
                int rr = idx >> 5, cc = (idx & 31) * 4;
                const float4 kv = ((const float4*)(K + ((size_t)h * SEQ + kt + rr) * DH))[idx & 31];
                const float4 vv = ((const float4*)(V + ((size_t)h * SEQ + kt + rr) * DH))[idx & 31];
                *(float4*)&KsS[rr][cc] = kv;
                *(float4*)&VsS[rr][cc] = vv;
            }
            __syncthreads();

            const int kglob = kt + key_l;
            float dot = 0.f;
            #pragma unroll
            for (int i = 0; i < 16; ++i) {
                float4 k4 = *(const float4*)&KsS[key_l][half * 64 + i * 4];
                dot += qreg[i].x * k4.x + qreg[i].y * k4.y + qreg[i].z * k4.z + qreg[i].w * k4.w;
            }
            dot += __shfl_xor(dot, 32);
            float logit = dot * SCALE;

            if (masked) {
                if (kglob >= TRI) {
                    logit += 1.5f + (ref_mask[(size_t)(kglob - TRI) * TRI + row] - 1.f) * 100.f;
                    if (row >= TRE)
                        logit += (routing[((kglob - TRI) >> 8) * IMG + (row - TRE)] - 1.f) * 100.f;
                } else if (kglob >= TXT && kglob < TRE && row >= TRE) {
                    logit += (routing[((kglob - TXT) >> 5) * IMG + (row - TRE)] - 1.f) * 100.f;
                }
            }

            float tm = logit;
            tm = fmaxf(tm, __shfl_xor(tm, 1));
            tm = fmaxf(tm, __shfl_xor(tm, 2));
            tm = fmaxf(tm, __shfl_xor(tm, 4));
            tm = fmaxf(tm, __shfl_xor(tm, 8));
            tm = fmaxf(tm, __shfl_xor(tm, 16));
            const float nm   = fmaxf(m, tm);
            const float corr = __expf(m - nm);
            const float p    = __expf(logit - nm);
            float ps = p;
            ps += __shfl_xor(ps, 1);
            ps += __shfl_xor(ps, 2);
            ps += __shfl_xor(ps, 4);
            ps += __shfl_xor(ps, 8);
            ps += __shfl_xor(ps, 16);
            l = l * corr + ps;
            acc0 *= corr; acc1 *= corr;
            m = nm;

            #pragma unroll
            for (int k = 0; k < KT; ++k) {
                const float pk = __shfl(p, k);
                acc0 += pk * VsS[k][lane];
                acc1 += pk * VsS[k][lane + 64];
            }
        }
    }

    const float inv = 1.f / l;
    float* op = out + ((size_t)h * SEQ + row) * DH;
    op[lane]      = acc0 * inv;
    op[lane + 64] = acc1 * inv;
}

extern "C" void kernel_launch(void* const* d_in, const int* in_sizes, int n_in,
                              void* d_out, int out_size, void* d_ws, size_t ws_size,
                              hipStream_t stream) {
    const float* Q        = (const float*)d_in[0];
    const float* K        = (const float*)d_in[1];
    const float* V        = (const float*)d_in[2];
    const float* ref_mask = (const float*)d_in[3];
    const float* routing  = (const float*)d_in[4];
    float* out = (float*)d_out;

    const size_t elems = (size_t)NH * SEQ * DH;
    const size_t need  = 2 * elems * sizeof(short);

    if (ws_size < need) {
        dim3 grid(SEQ / 4, NH);
        anystory_attn_scalar<<<grid, 256, 0, stream>>>(Q, K, V, ref_mask, routing, out, 0);
        return;
    }

    short* Kb  = (short*)d_ws;
    short* Vtg = Kb + elems;

    cvt_kv_kernel<<<dim3(SEQ / 16, NH), 256, 0, stream>>>(K, V, Kb, Vtg);

    // 26 block-cols per head (21 heavy, 1 router, 4 ref), head-major for XCD L2 locality
    attn_mfma<<<dim3(NH * 26), 512, 0, stream>>>(Q, Kb, Vtg, ref_mask, routing, out);
}

// Round 8
// 231.076 us; speedup vs baseline: 2.9996x; 2.9996x over previous
//
#include <hip/hip_runtime.h>
#include <hip/hip_bf16.h>

#define TXT   512
#define REDUX 64
#define IMG   2048
#define REFN  512
#define NC    2
#define SEQ   3168
#define DH    128
#define NH    24
#define TRE   576
#define TRI   2624
#define TRIR  3136
#define SCALE 0.08838834764831845f
#define L2E   1.4426950408889634f
#define QSC   (SCALE * L2E)          // scale folded with log2(e)
#define C100  (100.0f * L2E)         // 144.2695
#define CREF  (98.5f * L2E)          // 142.1055
#define THR2  (4.0f * L2E)           // defer-max threshold in log2 units

using f32x4  = __attribute__((ext_vector_type(4))) float;
using short8 = __attribute__((ext_vector_type(8))) short;

__device__ inline short f2bf(float x) {
    union { __hip_bfloat16 b; short s; } u;
    u.b = __float2bfloat16(x);
    return u.s;
}

__device__ inline void gload16(const short* g, short* l) {
    __builtin_amdgcn_global_load_lds(
        (const __attribute__((address_space(1))) unsigned int*)g,
        (__attribute__((address_space(3))) unsigned int*)l, 16, 0, 0);
}

// ---------------- fused pre-pass: K f32->bf16 linear, V f32->bf16 transposed ----------------
__global__ void cvt_kv_kernel(const float* __restrict__ K, const float* __restrict__ V,
                              short* __restrict__ Kb, short* __restrict__ Vt) {
    const int h   = blockIdx.y;
    const int tid = threadIdx.x;
    {
        const int base = ((h * SEQ + blockIdx.x * 16) * DH) >> 2;   // float4 idx
        #pragma unroll
        for (int j = 0; j < 2; ++j) {
            const int i = base + tid + j * 256;
            const float4 v = ((const float4*)K)[i];
            short4 o;
            o.x = f2bf(v.x); o.y = f2bf(v.y); o.z = f2bf(v.z); o.w = f2bf(v.w);
            ((short4*)Kb)[i] = o;
        }
    }
    {
        const int s8 = blockIdx.x * 2 + (tid >> 7);
        const int d  = tid & 127;
        const int s0 = s8 * 8;
        const float* src = V + ((size_t)h * SEQ + s0) * DH + d;
        short8 w;
        #pragma unroll
        for (int j = 0; j < 8; ++j) w[j] = f2bf(src[j * DH]);
        short* dst = Vt + ((size_t)h * DH + d) * SEQ + s0;
        *(short8*)dst = w;
    }
}

// ---------------- MFMA flash attention: swapped-QK, lane-local softmax ----------------
__global__ __launch_bounds__(512, 4)
void attn_mfma(const float* __restrict__ Q, const short* __restrict__ Kb,
               const short* __restrict__ Vtg, const float* __restrict__ ref_mask,
               const float* __restrict__ routing, float* __restrict__ out)
{
    __shared__ short Ks[64 * 128];     // [key][chunk^(key&7)] bf16
    __shared__ short Vs[128 * 64];     // [d][kc^(d&7)] bf16

    const int bid  = blockIdx.x;
    const int h    = bid % NH;          // same head -> same (bid%8) -> same XCD
    const int bx   = bid / NH;          // 0..25, heavy blocks dispatch first
    const int tid  = threadIdx.x;
    const int wave = tid >> 6, lane = tid & 63;
    const int g    = lane >> 4, l4 = lane & 15;

    int qbase, ks0 = 0, ntiles;
    bool masked = false, router = false;
    if (bx < 21)       { qbase = bx * 128; ntiles = 49; masked = true; }
    else if (bx == 21) { qbase = TRIR; ntiles = 33; router = true; }
    else {
        const int b2 = bx - 22;
        qbase = TRI + b2 * 128;
        ks0 = TRI + (b2 >> 1) * 256; ntiles = 4;
    }

    const int rbase = qbase + wave * 16;             // this wave's 16 q rows
    const bool valid = !(masked && rbase >= TRI) && !(router && wave >= 2);

    // ---- staging address precompute (pre-swizzled global source, linear LDS dest) ----
    const short* KbH = Kb  + (size_t)h * SEQ * DH;
    const short* VtH = Vtg + (size_t)h * DH * SEQ;
    int koff[2], vD[2], vKC[2], voff[2];
    #pragma unroll
    for (int j = 0; j < 2; ++j) {
        const int ci = tid + j * 512;
        const int kk = ci >> 4, kc = ci & 15;
        koff[j] = kk * 128 + ((kc ^ (kk & 7)) << 3);
        const int vd = ci >> 3, vk = ci & 7;
        vD[j] = vd; vKC[j] = vk;
        voff[j] = vd * SEQ + ((vk ^ (vd & 7)) << 3);
    }
    short* ksd0 = Ks + (size_t)(wave * 64) * 8;
    short* ksd1 = Ks + (size_t)(512 + wave * 64) * 8;
    short* vsd0 = Vs + (size_t)(wave * 64) * 8;
    short* vsd1 = Vs + (size_t)(512 + wave * 64) * 8;

    // ---- Q fragments (pre-scaled to log2 domain, bf16): row = l4, k-chunk = ks*4+g ----
    short8 qA[4];
    if (valid) {
        const int q = rbase + l4;
        const float* qp = Q + ((size_t)h * SEQ + q) * DH;
        #pragma unroll
        for (int ks = 0; ks < 4; ++ks) {
            const float4 a = *(const float4*)(qp + ks * 32 + g * 8);
            const float4 b = *(const float4*)(qp + ks * 32 + g * 8 + 4);
            short8 f;
            f[0] = f2bf(a.x * QSC); f[1] = f2bf(a.y * QSC);
            f[2] = f2bf(a.z * QSC); f[3] = f2bf(a.w * QSC);
            f[4] = f2bf(b.x * QSC); f[5] = f2bf(b.y * QSC);
            f[6] = f2bf(b.z * QSC); f[7] = f2bf(b.w * QSC);
            qA[ks] = f;
        }
    }

    f32x4 acc[8] = {};
    float m_run = -3.0e38f, l_run = 0.f;             // per q = rbase + l4 (lane-local)
    const int bsrc = (lane >> 4) << 2;               // bpermute source base g*4

    for (int t = 0; t < ntiles; ++t) {
        const int kt = masked ? t * 64
                     : (router ? (t < 32 ? TRE + t * 64 : TRIR) : ks0 + t * 64);
        const bool tail = router && (t == 32);       // only 32 of 64 keys valid
        __syncthreads();                             // A: previous tile consumed
        const short* kb = KbH + (size_t)kt * DH;
        const short* vb = VtH + kt;
        {
            const int ko0 = tail ? (koff[0] & 4095) : koff[0];
            const int ko1 = tail ? (koff[1] & 4095) : koff[1];
            gload16(kb + ko0, ksd0);
            gload16(kb + ko1, ksd1);
            const int vo0 = tail ? (vD[0] * SEQ + (((vKC[0] ^ (vD[0] & 7)) & 3) << 3)) : voff[0];
            const int vo1 = tail ? (vD[1] * SEQ + (((vKC[1] ^ (vD[1] & 7)) & 3) << 3)) : voff[1];
            gload16(vb + vo0, vsd0);
            gload16(vb + vo1, vsd1);
        }
        __syncthreads();                             // B: drains vmcnt + barrier

        if (!valid) continue;

        // ---- QK^T swapped: s[nt][r] = S[key = nt*16 + g*4 + r][q = rbase + l4] ----
        f32x4 s[4] = {};
        __builtin_amdgcn_s_setprio(1);
        #pragma unroll
        for (int nt = 0; nt < 4; ++nt) {
            const int key = nt * 16 + l4;
            #pragma unroll
            for (int ks = 0; ks < 4; ++ks) {
                const short8 kB = *(const short8*)(Ks + key * 128 + (((ks * 4 + g) ^ (key & 7)) << 3));
                s[nt] = __builtin_amdgcn_mfma_f32_16x16x32_bf16(kB, qA[ks], s[nt], 0, 0, 0);
            }
        }
        __builtin_amdgcn_s_setprio(0);

        // ---- masks (f32 exact, log2 domain), swapped orientation ----
        if (masked) {
            if (kt >= TRI) {                         // ref-key tiles
                const int cr = (kt - TRI) >> 8;
                const int q  = rbase + l4;
                const bool hr = rbase >= TRE;
                float radd = 0.f;
                if (hr) radd = routing[cr * IMG + (q - TRE)] * C100 - C100;
                const int j0 = kt - TRI + g * 4;
                #pragma unroll
                for (int nt = 0; nt < 4; ++nt)
                    #pragma unroll
                    for (int r = 0; r < 4; ++r) {
                        const float rmv = ref_mask[(size_t)(j0 + nt * 16 + r) * TRI + q];
                        s[nt][r] += rmv * C100 - CREF + radd;
                    }
            } else if (kt == TXT) {                  // redux-key tile
                if (rbase >= TRE) {
                    const int q = rbase + l4;
                    const float a0 = routing[q - TRE] * C100 - C100;
                    const float a1 = routing[IMG + q - TRE] * C100 - C100;
                    #pragma unroll
                    for (int nt = 0; nt < 4; ++nt)
                        #pragma unroll
                        for (int r = 0; r < 4; ++r)
                            s[nt][r] += (nt >> 1) ? a1 : a0;
                }
            }
        }
        if (tail) {                                  // router tail: keys >= SEQ invalid
            #pragma unroll
            for (int r = 0; r < 4; ++r) { s[2][r] = -3.0e38f; s[3][r] = -3.0e38f; }
        }

        // ---- softmax: lane-local (16 keys in-reg) + 2 cross-g shuffles ----
        float mx = fmaxf(fmaxf(s[0][0], s[0][1]), fmaxf(s[0][2], s[0][3]));
        mx = fmaxf(mx, fmaxf(fmaxf(s[1][0], s[1][1]), fmaxf(s[1][2], s[1][3])));
        mx = fmaxf(mx, fmaxf(fmaxf(s[2][0], s[2][1]), fmaxf(s[2][2], s[2][3])));
        mx = fmaxf(mx, fmaxf(fmaxf(s[3][0], s[3][1]), fmaxf(s[3][2], s[3][3])));
        mx = fmaxf(mx, __shfl_xor(mx, 16));
        mx = fmaxf(mx, __shfl_xor(mx, 32));

        if (__any(mx - m_run > THR2)) {              // defer-max rescale (rare)
            const float mn    = fmaxf(m_run, mx);
            const float corrq = exp2f(m_run - mn);
            m_run = mn;
            l_run *= corrq;
            f32x4 corr;                               // broadcast corr to acc rows q=g*4+r
            #pragma unroll
            for (int r = 0; r < 4; ++r) corr[r] = __shfl(corrq, bsrc + r);
            #pragma unroll
            for (int nt = 0; nt < 8; ++nt)
                #pragma unroll
                for (int r = 0; r < 4; ++r) acc[nt][r] *= corr[r];
        }

        float rsum = 0.f;
        #pragma unroll
        for (int nt = 0; nt < 4; ++nt)
            #pragma unroll
            for (int r = 0; r < 4; ++r) {
                s[nt][r] = exp2f(s[nt][r] - m_run);
                rsum += s[nt][r];
            }
        rsum += __shfl_xor(rsum, 16);
        rsum += __shfl_xor(rsum, 32);
        l_run += rsum;

        // ---- pack P in-lane: pA slots use lambda(g,i) = ks2*32 + (i<4 ? g*4+i : 16+g*4+i-4) ----
        short8 pA0, pA1;
        #pragma unroll
        for (int j = 0; j < 4; ++j) {
            pA0[j]     = f2bf(s[0][j]);
            pA0[4 + j] = f2bf(s[1][j]);
            pA1[j]     = f2bf(s[2][j]);
            pA1[4 + j] = f2bf(s[3][j]);
        }

        // ---- PV: vB supplies V[lambda(g,i)][d] via two b64 reads of 4-consecutive keys ----
        __builtin_amdgcn_s_setprio(1);
        #pragma unroll
        for (int ks2 = 0; ks2 < 2; ++ks2) {
            const short8 pa = ks2 ? pA1 : pA0;
            const int kcA = ks2 * 4 + (g >> 1);      // chunk of keys ks2*32 + g*4
            const int eo  = (g & 1) << 2;            // element offset within chunk
            #pragma unroll
            for (int nt = 0; nt < 8; ++nt) {
                const int d = nt * 16 + l4;
                const short* vrow = Vs + d * 64;
                const short4 va  = *(const short4*)(vrow + ((kcA ^ (d & 7)) << 3) + eo);
                const short4 vb4 = *(const short4*)(vrow + (((kcA + 2) ^ (d & 7)) << 3) + eo);
                short8 vB;
                vB[0] = va.x;  vB[1] = va.y;  vB[2] = va.z;  vB[3] = va.w;
                vB[4] = vb4.x; vB[5] = vb4.y; vB[6] = vb4.z; vB[7] = vb4.w;
                acc[nt] = __builtin_amdgcn_mfma_f32_16x16x32_bf16(pa, vB, acc[nt], 0, 0, 0);
            }
        }
        __builtin_amdgcn_s_setprio(0);
    }

    if (valid) {
        f32x4 linv;                                  // 1/l for acc rows q = g*4+r
        #pragma unroll
        for (int r = 0; r < 4; ++r) linv[r] = 1.0f / __shfl(l_run, bsrc + r);
        #pragma unroll
        for (int nt = 0; nt < 8; ++nt)
            #pragma unroll
            for (int r = 0; r < 4; ++r) {
                const int q = rbase + g * 4 + r;
                out[((size_t)h * SEQ + q) * DH + nt * 16 + l4] = acc[nt][r] * linv[r];
            }
    }
}

// ---------------- scalar kernel (full fallback only) ----------------
#define KT  32
#define LDK (DH + 4)
__global__ __launch_bounds__(256, 2)
void anystory_attn_scalar(const float* __restrict__ Q, const float* __restrict__ K,
                          const float* __restrict__ V, const float* __restrict__ ref_mask,
                          const float* __restrict__ routing, float* __restrict__ out, int row0)
{
    __shared__ float KsS[KT][LDK];
    __shared__ float VsS[KT][LDK];

    const int h    = blockIdx.y;
    const int r0   = row0 + blockIdx.x * 4;
    const int tid  = threadIdx.x;
    const int wave = tid >> 6;
    const int lane = tid & 63;
    const int key_l = lane & 31;
    const int half  = lane >> 5;
    const int row  = r0 + wave;

    int rs0, re0, rs1 = 0, re1 = 0;
    bool masked = false;
    if (r0 < TRI) { rs0 = 0; re0 = TRIR; masked = true; }
    else if (r0 < TRIR) {
        int c = (r0 - TRI) / (REFN / NC);
        rs0 = TRI + c * (REFN / NC); re0 = rs0 + (REFN / NC);
    } else { rs0 = TRE; re0 = TRI; rs1 = TRIR; re1 = SEQ; }

    float4 qreg[16];
    const float4* qptr = (const float4*)(Q + ((size_t)h * SEQ + row) * DH + half * 64);
    #pragma unroll
    for (int i = 0; i < 16; ++i) qreg[i] = qptr[i];

    float m = -1e30f, l = 0.f, acc0 = 0.f, acc1 = 0.f;

    for (int range = 0; range < 2; ++range) {
        const int ks = (range == 0) ? rs0 : rs1;
        const int ke = (range == 0) ? re0 : re1;
        for (int kt = ks; kt < ke; kt += KT) {
            __syncthreads();
            #pragma unroll
            for (int i = 0; i < 4; ++i) {
                int idx = tid + i * 256;
                int rr = idx >> 5, cc = (idx & 31) * 4;
                const float4 kv = ((const float4*)(K + ((size_t)h * SEQ + kt + rr) * DH))[idx & 31];
                const float4 vv = ((const float4*)(V + ((size_t)h * SEQ + kt + rr) * DH))[idx & 31];
                *(float4*)&KsS[rr][cc] = kv;
                *(float4*)&VsS[rr][cc] = vv;
            }
            __syncthreads();

            const int kglob = kt + key_l;
            float dot = 0.f;
            #pragma unroll
            for (int i = 0; i < 16; ++i) {
                float4 k4 = *(const float4*)&KsS[key_l][half * 64 + i * 4];
                dot += qreg[i].x * k4.x + qreg[i].y * k4.y + qreg[i].z * k4.z + qreg[i].w * k4.w;
            }
            dot += __shfl_xor(dot, 32);
            float logit = dot * SCALE;

            if (masked) {
                if (kglob >= TRI) {
                    logit += 1.5f + (ref_mask[(size_t)(kglob - TRI) * TRI + row] - 1.f) * 100.f;
                    if (row >= TRE)
                        logit += (routing[((kglob - TRI) >> 8) * IMG + (row - TRE)] - 1.f) * 100.f;
                } else if (kglob >= TXT && kglob < TRE && row >= TRE) {
                    logit += (routing[((kglob - TXT) >> 5) * IMG + (row - TRE)] - 1.f) * 100.f;
                }
            }

            float tm = logit;
            tm = fmaxf(tm, __shfl_xor(tm, 1));
            tm = fmaxf(tm, __shfl_xor(tm, 2));
            tm = fmaxf(tm, __shfl_xor(tm, 4));
            tm = fmaxf(tm, __shfl_xor(tm, 8));
            tm = fmaxf(tm, __shfl_xor(tm, 16));
            const float nm   = fmaxf(m, tm);
            const float corr = __expf(m - nm);
            const float p    = __expf(logit - nm);
            float ps = p;
            ps += __shfl_xor(ps, 1);
            ps += __shfl_xor(ps, 2);
            ps += __shfl_xor(ps, 4);
            ps += __shfl_xor(ps, 8);
            ps += __shfl_xor(ps, 16);
            l = l * corr + ps;
            acc0 *= corr; acc1 *= corr;
            m = nm;

            #pragma unroll
            for (int k = 0; k < KT; ++k) {
                const float pk = __shfl(p, k);
                acc0 += pk * VsS[k][lane];
                acc1 += pk * VsS[k][lane + 64];
            }
        }
    }

    const float inv = 1.f / l;
    float* op = out + ((size_t)h * SEQ + row) * DH;
    op[lane]      = acc0 * inv;
    op[lane + 64] = acc1 * inv;
}

extern "C" void kernel_launch(void* const* d_in, const int* in_sizes, int n_in,
                              void* d_out, int out_size, void* d_ws, size_t ws_size,
                              hipStream_t stream) {
    const float* Q        = (const float*)d_in[0];
    const float* K        = (const float*)d_in[1];
    const float* V        = (const float*)d_in[2];
    const float* ref_mask = (const float*)d_in[3];
    const float* routing  = (const float*)d_in[4];
    float* out = (float*)d_out;

    const size_t elems = (size_t)NH * SEQ * DH;
    const size_t need  = 2 * elems * sizeof(short);

    if (ws_size < need) {
        dim3 grid(SEQ / 4, NH);
        anystory_attn_scalar<<<grid, 256, 0, stream>>>(Q, K, V, ref_mask, routing, out, 0);
        return;
    }

    short* Kb  = (short*)d_ws;
    short* Vtg = Kb + elems;

    cvt_kv_kernel<<<dim3(SEQ / 16, NH), 256, 0, stream>>>(K, V, Kb, Vtg);

    // 26 block-cols per head (21 heavy, 1 router, 4 ref), head-major for XCD L2 locality
    attn_mfma<<<dim3(NH * 26), 512, 0, stream>>>(Q, Kb, Vtg, ref_mask, routing, out);
}

// Round 9
// 218.157 us; speedup vs baseline: 3.1772x; 1.0592x over previous
//
#include <hip/hip_runtime.h>
#include <hip/hip_bf16.h>

#define TXT   512
#define REDUX 64
#define IMG   2048
#define REFN  512
#define NC    2
#define SEQ   3168
#define DH    128
#define NH    24
#define TRE   576
#define TRI   2624
#define TRIR  3136
#define SCALE 0.08838834764831845f
#define L2E   1.4426950408889634f
#define QSC   (SCALE * L2E)          // scale folded with log2(e)
#define C100  (100.0f * L2E)         // 144.2695
#define CREF  (98.5f * L2E)          // 142.1055
#define THR2  (4.0f * L2E)           // defer-max threshold in log2 units

using f32x4  = __attribute__((ext_vector_type(4))) float;
using short8 = __attribute__((ext_vector_type(8))) short;

__device__ inline short f2bf(float x) {
    union { __hip_bfloat16 b; short s; } u;
    u.b = __float2bfloat16(x);
    return u.s;
}

__device__ inline void gload16(const short* g, short* l) {
    __builtin_amdgcn_global_load_lds(
        (const __attribute__((address_space(1))) unsigned int*)g,
        (__attribute__((address_space(3))) unsigned int*)l, 16, 0, 0);
}

// ---------------- fused pre-pass: K f32->bf16 linear, V f32->bf16 transposed+permuted ----
// Vt[h][d][pos] with key order permuted within each 64-key tile:
//   pos = ks2*32 + g*8 + (i<4 ? i : 4+i-4) maps key lambda(g,i) = ks2*32 + (i<4 ? g*4+i
//   : 16+g*4+(i-4)), so the PV B-fragment for MFMA slot block g is one contiguous chunk.
__global__ void cvt_kv_kernel(const float* __restrict__ K, const float* __restrict__ V,
                              short* __restrict__ Kb, short* __restrict__ Vt) {
    const int h   = blockIdx.y;
    const int tid = threadIdx.x;
    {
        const int base = ((h * SEQ + blockIdx.x * 16) * DH) >> 2;   // float4 idx
        #pragma unroll
        for (int j = 0; j < 2; ++j) {
            const int i = base + tid + j * 256;
            const float4 v = ((const float4*)K)[i];
            short4 o;
            o.x = f2bf(v.x); o.y = f2bf(v.y); o.z = f2bf(v.z); o.w = f2bf(v.w);
            ((short4*)Kb)[i] = o;
        }
    }
    {
        const int s8 = blockIdx.x * 2 + (tid >> 7);
        const int d  = tid & 127;
        const int s0 = s8 * 8;                       // 8 consecutive keys
        const float* src = V + ((size_t)h * SEQ + s0) * DH + d;
        short8 w;
        #pragma unroll
        for (int j = 0; j < 8; ++j) w[j] = f2bf(src[j * DH]);
        // permuted positions within the 64-key tile
        const int tb   = s0 & ~63;                   // tile base (tiles are 64-aligned)
        const int j0   = s0 & 63;                    // 0,8,16,...,56
        const int ks2  = j0 >> 5;
        const int jm   = j0 & 15;                    // 0 or 8
        const int hi   = (j0 >> 4) & 1;
        const int pos0 = ks2 * 32 + (jm >> 2) * 8 + hi * 4;
        short* dst = Vt + ((size_t)h * DH + d) * SEQ + tb;
        short4 lo4, hi4;
        lo4.x = w[0]; lo4.y = w[1]; lo4.z = w[2]; lo4.w = w[3];
        hi4.x = w[4]; hi4.y = w[5]; hi4.z = w[6]; hi4.w = w[7];
        *(short4*)(dst + pos0)     = lo4;            // keys j0+0..3
        *(short4*)(dst + pos0 + 8) = hi4;            // keys j0+4..7
    }
}

// ---------------- MFMA flash attention: swapped-QK, lane-local softmax ----------------
__global__ __launch_bounds__(512, 4)
void attn_mfma(const float* __restrict__ Q, const short* __restrict__ Kb,
               const short* __restrict__ Vtg, const float* __restrict__ ref_mask,
               const float* __restrict__ routing, float* __restrict__ out)
{
    __shared__ short Ks[64 * 128];     // [key][chunk^(key&7)] bf16
    __shared__ short Vs[128 * 64];     // [d][kc^(d&7)] bf16 (keys in lambda-permuted order)

    const int bid  = blockIdx.x;
    const int h    = bid % NH;          // same head -> same (bid%8) -> same XCD
    const int bx   = bid / NH;          // 0..25, heavy blocks dispatch first
    const int tid  = threadIdx.x;
    const int wave = tid >> 6, lane = tid & 63;
    const int g    = lane >> 4, l4 = lane & 15;

    int qbase, ks0 = 0, ntiles;
    bool masked = false, router = false;
    if (bx < 21)       { qbase = bx * 128; ntiles = 49; masked = true; }
    else if (bx == 21) { qbase = TRIR; ntiles = 33; router = true; }
    else {
        const int b2 = bx - 22;
        qbase = TRI + b2 * 128;
        ks0 = TRI + (b2 >> 1) * 256; ntiles = 4;
    }

    const int rbase = qbase + wave * 16;             // this wave's 16 q rows
    const bool valid = !(masked && rbase >= TRI) && !(router && wave >= 2);

    // ---- staging address precompute (pre-swizzled global source, linear LDS dest) ----
    const short* KbH = Kb  + (size_t)h * SEQ * DH;
    const short* VtH = Vtg + (size_t)h * DH * SEQ;
    int koff[2], vD[2], vKC[2], voff[2];
    #pragma unroll
    for (int j = 0; j < 2; ++j) {
        const int ci = tid + j * 512;
        const int kk = ci >> 4, kc = ci & 15;
        koff[j] = kk * 128 + ((kc ^ (kk & 7)) << 3);
        const int vd = ci >> 3, vk = ci & 7;
        vD[j] = vd; vKC[j] = vk;
        voff[j] = vd * SEQ + ((vk ^ (vd & 7)) << 3);
    }
    short* ksd0 = Ks + (size_t)(wave * 64) * 8;
    short* ksd1 = Ks + (size_t)(512 + wave * 64) * 8;
    short* vsd0 = Vs + (size_t)(wave * 64) * 8;
    short* vsd1 = Vs + (size_t)(512 + wave * 64) * 8;

    // ---- Q fragments (pre-scaled to log2 domain, bf16): row = l4, k-chunk = ks*4+g ----
    short8 qA[4];
    if (valid) {
        const int q = rbase + l4;
        const float* qp = Q + ((size_t)h * SEQ + q) * DH;
        #pragma unroll
        for (int ks = 0; ks < 4; ++ks) {
            const float4 a = *(const float4*)(qp + ks * 32 + g * 8);
            const float4 b = *(const float4*)(qp + ks * 32 + g * 8 + 4);
            short8 f;
            f[0] = f2bf(a.x * QSC); f[1] = f2bf(a.y * QSC);
            f[2] = f2bf(a.z * QSC); f[3] = f2bf(a.w * QSC);
            f[4] = f2bf(b.x * QSC); f[5] = f2bf(b.y * QSC);
            f[6] = f2bf(b.z * QSC); f[7] = f2bf(b.w * QSC);
            qA[ks] = f;
        }
    }

    f32x4 acc[8] = {};
    float m_run = -3.0e38f, l_run = 0.f;             // per q = rbase + l4 (lane-local)
    const int bsrc = (lane >> 4) << 2;               // shuffle source base g*4

    for (int t = 0; t < ntiles; ++t) {
        const int kt = masked ? t * 64
                     : (router ? (t < 32 ? TRE + t * 64 : TRIR) : ks0 + t * 64);
        const bool tail = router && (t == 32);       // only 32 of 64 keys valid
        __syncthreads();                             // A: previous tile consumed
        const short* kb = KbH + (size_t)kt * DH;
        const short* vb = VtH + kt;
        {
            const int ko0 = tail ? (koff[0] & 4095) : koff[0];
            const int ko1 = tail ? (koff[1] & 4095) : koff[1];
            gload16(kb + ko0, ksd0);
            gload16(kb + ko1, ksd1);
            const int vo0 = tail ? (vD[0] * SEQ + (((vKC[0] ^ (vD[0] & 7)) & 3) << 3)) : voff[0];
            const int vo1 = tail ? (vD[1] * SEQ + (((vKC[1] ^ (vD[1] & 7)) & 3) << 3)) : voff[1];
            gload16(vb + vo0, vsd0);
            gload16(vb + vo1, vsd1);
        }
        __syncthreads();                             // B: drains vmcnt + barrier

        if (!valid) continue;

        // ---- QK^T swapped: s[nt][r] = S[key = nt*16 + g*4 + r][q = rbase + l4] ----
        f32x4 s[4] = {};
        __builtin_amdgcn_s_setprio(1);
        #pragma unroll
        for (int nt = 0; nt < 4; ++nt) {
            const int key = nt * 16 + l4;
            #pragma unroll
            for (int ks = 0; ks < 4; ++ks) {
                const short8 kB = *(const short8*)(Ks + key * 128 + (((ks * 4 + g) ^ (key & 7)) << 3));
                s[nt] = __builtin_amdgcn_mfma_f32_16x16x32_bf16(kB, qA[ks], s[nt], 0, 0, 0);
            }
        }
        __builtin_amdgcn_s_setprio(0);

        // ---- masks (f32 exact, log2 domain), swapped orientation ----
        if (masked) {
            if (kt >= TRI) {                         // ref-key tiles
                const int cr = (kt - TRI) >> 8;
                const int q  = rbase + l4;
                const bool hr = rbase >= TRE;
                float radd = 0.f;
                if (hr) radd = routing[cr * IMG + (q - TRE)] * C100 - C100;
                const int j0 = kt - TRI + g * 4;
                #pragma unroll
                for (int nt = 0; nt < 4; ++nt)
                    #pragma unroll
                    for (int r = 0; r < 4; ++r) {
                        const float rmv = ref_mask[(size_t)(j0 + nt * 16 + r) * TRI + q];
                        s[nt][r] += rmv * C100 - CREF + radd;
                    }
            } else if (kt == TXT) {                  // redux-key tile
                if (rbase >= TRE) {
                    const int q = rbase + l4;
                    const float a0 = routing[q - TRE] * C100 - C100;
                    const float a1 = routing[IMG + q - TRE] * C100 - C100;
                    #pragma unroll
                    for (int nt = 0; nt < 4; ++nt)
                        #pragma unroll
                        for (int r = 0; r < 4; ++r)
                            s[nt][r] += (nt >> 1) ? a1 : a0;
                }
            }
        }
        if (tail) {                                  // router tail: keys >= SEQ invalid
            #pragma unroll
            for (int r = 0; r < 4; ++r) { s[2][r] = -3.0e38f; s[3][r] = -3.0e38f; }
        }

        // ---- softmax: lane-local (16 keys in-reg) + 2 cross-group shuffles ----
        float mx = fmaxf(fmaxf(s[0][0], s[0][1]), fmaxf(s[0][2], s[0][3]));
        mx = fmaxf(mx, fmaxf(fmaxf(s[1][0], s[1][1]), fmaxf(s[1][2], s[1][3])));
        mx = fmaxf(mx, fmaxf(fmaxf(s[2][0], s[2][1]), fmaxf(s[2][2], s[2][3])));
        mx = fmaxf(mx, fmaxf(fmaxf(s[3][0], s[3][1]), fmaxf(s[3][2], s[3][3])));
        mx = fmaxf(mx, __shfl_xor(mx, 16));
        mx = fmaxf(mx, __shfl_xor(mx, 32));

        if (__any(mx - m_run > THR2)) {              // defer-max rescale (rare)
            const float mn    = fmaxf(m_run, mx);
            const float corrq = exp2f(m_run - mn);
            m_run = mn;
            l_run *= corrq;
            f32x4 corr;                               // broadcast corr to acc rows q=g*4+r
            #pragma unroll
            for (int r = 0; r < 4; ++r) corr[r] = __shfl(corrq, bsrc + r);
            #pragma unroll
            for (int nt = 0; nt < 8; ++nt)
                #pragma unroll
                for (int r = 0; r < 4; ++r) acc[nt][r] *= corr[r];
        }

        float rsum = 0.f;
        #pragma unroll
        for (int nt = 0; nt < 4; ++nt)
            #pragma unroll
            for (int r = 0; r < 4; ++r) {
                s[nt][r] = exp2f(s[nt][r] - m_run);
                rsum += s[nt][r];
            }
        rsum += __shfl_xor(rsum, 16);
        rsum += __shfl_xor(rsum, 32);
        l_run += rsum;

        // ---- pack P in-lane: pA slots = lambda(g,i) = ks2*32 + (i<4 ? g*4+i : 16+g*4+i-4) ----
        short8 pA0, pA1;
        #pragma unroll
        for (int j = 0; j < 4; ++j) {
            pA0[j]     = f2bf(s[0][j]);
            pA0[4 + j] = f2bf(s[1][j]);
            pA1[j]     = f2bf(s[2][j]);
            pA1[4 + j] = f2bf(s[3][j]);
        }

        // ---- PV: Vs is lambda-permuted, so B-fragment = one b128 chunk read ----
        __builtin_amdgcn_s_setprio(1);
        #pragma unroll
        for (int ks2 = 0; ks2 < 2; ++ks2) {
            const short8 pa = ks2 ? pA1 : pA0;
            const int kc = ks2 * 4 + g;              // permuted chunk holding lambda(g,0..7)
            #pragma unroll
            for (int nt = 0; nt < 8; ++nt) {
                const int d = nt * 16 + l4;
                const short8 vB = *(const short8*)(Vs + d * 64 + ((kc ^ (d & 7)) << 3));
                acc[nt] = __builtin_amdgcn_mfma_f32_16x16x32_bf16(pa, vB, acc[nt], 0, 0, 0);
            }
        }
        __builtin_amdgcn_s_setprio(0);
    }

    if (valid) {
        f32x4 linv;                                  // 1/l for acc rows q = g*4+r
        #pragma unroll
        for (int r = 0; r < 4; ++r) linv[r] = 1.0f / __shfl(l_run, bsrc + r);
        #pragma unroll
        for (int nt = 0; nt < 8; ++nt)
            #pragma unroll
            for (int r = 0; r < 4; ++r) {
                const int q = rbase + g * 4 + r;
                out[((size_t)h * SEQ + q) * DH + nt * 16 + l4] = acc[nt][r] * linv[r];
            }
    }
}

// ---------------- scalar kernel (full fallback only; uses raw f32 K/V) ----------------
#define KT  32
#define LDK (DH + 4)
__global__ __launch_bounds__(256, 2)
void anystory_attn_scalar(const float* __restrict__ Q, const float* __restrict__ K,
                          const float* __restrict__ V, const float* __restrict__ ref_mask,
                          const float* __restrict__ routing, float* __restrict__ out, int row0)
{
    __shared__ float KsS[KT][LDK];
    __shared__ float VsS[KT][LDK];

    const int h    = blockIdx.y;
    const int r0   = row0 + blockIdx.x * 4;
    const int tid  = threadIdx.x;
    const int wave = tid >> 6;
    const int lane = tid & 63;
    const int key_l = lane & 31;
    const int half  = lane >> 5;
    const int row  = r0 + wave;

    int rs0, re0, rs1 = 0, re1 = 0;
    bool masked = false;
    if (r0 < TRI) { rs0 = 0; re0 = TRIR; masked = true; }
    else if (r0 < TRIR) {
        int c = (r0 - TRI) / (REFN / NC);
        rs0 = TRI + c * (REFN / NC); re0 = rs0 + (REFN / NC);
    } else { rs0 = TRE; re0 = TRI; rs1 = TRIR; re1 = SEQ; }

    float4 qreg[16];
    const float4* qptr = (const float4*)(Q + ((size_t)h * SEQ + row) * DH + half * 64);
    #pragma unroll
    for (int i = 0; i < 16; ++i) qreg[i] = qptr[i];

    float m = -1e30f, l = 0.f, acc0 = 0.f, acc1 = 0.f;

    for (int range = 0; range < 2; ++range) {
        const int ks = (range == 0) ? rs0 : rs1;
        const int ke = (range == 0) ? re0 : re1;
        for (int kt = ks; kt < ke; kt += KT) {
            __syncthreads();
            #pragma unroll
            for (int i = 0; i < 4; ++i) {
                int idx = tid + i * 256;
                int rr = idx >> 5, cc = (idx & 31) * 4;
                const float4 kv = ((const float4*)(K + ((size_t)h * SEQ + kt + rr) * DH))[idx & 31];
                const float4 vv = ((const float4*)(V + ((size_t)h * SEQ + kt + rr) * DH))[idx & 31];
                *(float4*)&KsS[rr][cc] = kv;
                *(float4*)&VsS[rr][cc] = vv;
            }
            __syncthreads();

            const int kglob = kt + key_l;
            float dot = 0.f;
            #pragma unroll
            for (int i = 0; i < 16; ++i) {
                float4 k4 = *(const float4*)&KsS[key_l][half * 64 + i * 4];
                dot += qreg[i].x * k4.x + qreg[i].y * k4.y + qreg[i].z * k4.z + qreg[i].w * k4.w;
            }
            dot += __shfl_xor(dot, 32);
            float logit = dot * SCALE;

            if (masked) {
                if (kglob >= TRI) {
                    logit += 1.5f + (ref_mask[(size_t)(kglob - TRI) * TRI + row] - 1.f) * 100.f;
                    if (row >= TRE)
                        logit += (routing[((kglob - TRI) >> 8) * IMG + (row - TRE)] - 1.f) * 100.f;
                } else if (kglob >= TXT && kglob < TRE && row >= TRE) {
                    logit += (routing[((kglob - TXT) >> 5) * IMG + (row - TRE)] - 1.f) * 100.f;
                }
            }

            float tm = logit;
            tm = fmaxf(tm, __shfl_xor(tm, 1));
            tm = fmaxf(tm, __shfl_xor(tm, 2));
            tm = fmaxf(tm, __shfl_xor(tm, 4));
            tm = fmaxf(tm, __shfl_xor(tm, 8));
            tm = fmaxf(tm, __shfl_xor(tm, 16));
            const float nm   = fmaxf(m, tm);
            const float corr = __expf(m - nm);
            const float p    = __expf(logit - nm);
            float ps = p;
            ps += __shfl_xor(ps, 1);
            ps += __shfl_xor(ps, 2);
            ps += __shfl_xor(ps, 4);
            ps += __shfl_xor(ps, 8);
            ps += __shfl_xor(ps, 16);
            l = l * corr + ps;
            acc0 *= corr; acc1 *= corr;
            m = nm;

            #pragma unroll
            for (int k = 0; k < KT; ++k) {
                const float pk = __shfl(p, k);
                acc0 += pk * VsS[k][lane];
                acc1 += pk * VsS[k][lane + 64];
            }
        }
    }

    const float inv = 1.f / l;
    float* op = out + ((size_t)h * SEQ + row) * DH;
    op[lane]      = acc0 * inv;
    op[lane + 64] = acc1 * inv;
}

extern "C" void kernel_launch(void* const* d_in, const int* in_sizes, int n_in,
                              void* d_out, int out_size, void* d_ws, size_t ws_size,
                              hipStream_t stream) {
    const float* Q        = (const float*)d_in[0];
    const float* K        = (const float*)d_in[1];
    const float* V        = (const float*)d_in[2];
    const float* ref_mask = (const float*)d_in[3];
    const float* routing  = (const float*)d_in[4];
    float* out = (float*)d_out;

    const size_t elems = (size_t)NH * SEQ * DH;
    const size_t need  = 2 * elems * sizeof(short);

    if (ws_size < need) {
        dim3 grid(SEQ / 4, NH);
        anystory_attn_scalar<<<grid, 256, 0, stream>>>(Q, K, V, ref_mask, routing, out, 0);
        return;
    }

    short* Kb  = (short*)d_ws;
    short* Vtg = Kb + elems;

    cvt_kv_kernel<<<dim3(SEQ / 16, NH), 256, 0, stream>>>(K, V, Kb, Vtg);

    // 26 block-cols per head (21 heavy, 1 router, 4 ref), head-major for XCD L2 locality
    attn_mfma<<<dim3(NH * 26), 512, 0, stream>>>(Q, Kb, Vtg, ref_mask, routing, out);
}